// Round 1
// baseline (251.478 us; speedup 1.0000x reference)
//
#include <hip/hip_runtime.h>

#define LOG2E 1.44269504088896340736f

typedef __attribute__((ext_vector_type(8))) short short8;
typedef __attribute__((ext_vector_type(4))) float float4v;
typedef __attribute__((ext_vector_type(4))) int int4v;

__device__ inline unsigned short f2bf(float f) {
    union { float f; unsigned u; } v; v.f = f;
    unsigned r = v.u + 0x7fffu + ((v.u >> 16) & 1u);
    return (unsigned short)(r >> 16);
}

// ---------------------------------------------------------------------------
// Kernel 1: projections.  Q[b][i][o]=sum_c a*wq (+bq), K from b/wk, V[b][c][i]
// from a/wv (+bv).  Q,K stored (N,32) bf16; V stored (C,N) bf16.
// grid 256 (batch = blk&3, tile = blk>>2), block 256.
// ---------------------------------------------------------------------------
__launch_bounds__(256, 1)
__global__ void proj_kernel(const float* __restrict__ a_p, const float* __restrict__ b_p,
                            const float* __restrict__ wq, const float* __restrict__ bq,
                            const float* __restrict__ wk, const float* __restrict__ bk,
                            const float* __restrict__ wv, const float* __restrict__ bv,
                            unsigned short* __restrict__ Qg, unsigned short* __restrict__ Kg,
                            unsigned short* __restrict__ Vg)
{
    __shared__ unsigned short At[64 * 264];   // a-tile transposed (i, c), bf16, pad 264
    __shared__ unsigned short Bt[64 * 264];   // b-tile transposed
    __shared__ unsigned short Wg[64 * 264];   // weight group rows (m, c)
    __shared__ float bias[320];               // bq(32) bk(32) bv(256)

    const int t    = threadIdx.x;
    const int blk  = blockIdx.x;
    const int b    = blk & 3;
    const int tile = blk >> 2;
    const int i0   = tile * 64;
    const int lane = t & 63;
    const int w    = t >> 6;
    const int q    = lane >> 4;
    const int n    = lane & 15;

    // ---- stage a,b tiles transposed to (i, c) bf16 ----
    for (int p = 0; p < 4; ++p) {
        int c  = p * 64 + (t >> 2);
        int ib = (t & 3) * 16;
        const float4v* sa = (const float4v*)(a_p + ((size_t)(b * 256 + c) * 4096 + i0 + ib));
        const float4v* sb = (const float4v*)(b_p + ((size_t)(b * 256 + c) * 4096 + i0 + ib));
#pragma unroll
        for (int k2 = 0; k2 < 4; ++k2) {
            float4v va = sa[k2];
            float4v vb = sb[k2];
#pragma unroll
            for (int j = 0; j < 4; ++j) {
                int ii = ib + k2 * 4 + j;
                At[ii * 264 + c] = f2bf(va[j]);
                Bt[ii * 264 + c] = f2bf(vb[j]);
            }
        }
    }
    for (int idx = t; idx < 320; idx += 256)
        bias[idx] = (idx < 32) ? bq[idx] : (idx < 64) ? bk[idx - 32] : bv[idx - 64];
    __syncthreads();

    for (int g = 0; g < 5; ++g) {
        // ---- load weight group (64 rows x 256 c) as bf16 ----
        {
            int row = t >> 2;
            int cc  = (t & 3) * 64;
            const float* src;
            if (g == 0) src = (row < 32) ? (wq + row * 256) : (wk + (row - 32) * 256);
            else        src = wv + ((size_t)((g - 1) * 64 + row)) * 256;
            const float4v* s4 = (const float4v*)(src + cc);
#pragma unroll
            for (int k2 = 0; k2 < 16; ++k2) {
                float4v v4 = s4[k2];
                int c = cc + 4 * k2;
                unsigned p0 = (unsigned)f2bf(v4[0]) | ((unsigned)f2bf(v4[1]) << 16);
                unsigned p1 = (unsigned)f2bf(v4[2]) | ((unsigned)f2bf(v4[3]) << 16);
                *(unsigned*)&Wg[row * 264 + c]     = p0;
                *(unsigned*)&Wg[row * 264 + c + 2] = p1;
            }
        }
        __syncthreads();

        // ---- GEMM: wave w handles i-cols [16w, 16w+16) ----
        float4v acc[4];
#pragma unroll
        for (int mt = 0; mt < 4; ++mt) acc[mt] = (float4v){0.f, 0.f, 0.f, 0.f};
#pragma unroll
        for (int kc = 0; kc < 8; ++kc) {
            short8 bfa = *(const short8*)&At[(16 * w + n) * 264 + kc * 32 + q * 8];
            short8 bfb = bfa;
            if (g == 0) bfb = *(const short8*)&Bt[(16 * w + n) * 264 + kc * 32 + q * 8];
#pragma unroll
            for (int mt = 0; mt < 4; ++mt) {
                short8 af = *(const short8*)&Wg[(mt * 16 + n) * 264 + kc * 32 + q * 8];
                short8 bsel = (g == 0 && mt >= 2) ? bfb : bfa;
                acc[mt] = __builtin_amdgcn_mfma_f32_16x16x32_bf16(af, bsel, acc[mt], 0, 0, 0);
            }
        }
        __syncthreads();   // before next group's Wg overwrite

        // ---- store: C-layout row = m = mt*16 + q*4 + r, col = i = 16w + n ----
        int i = i0 + 16 * w + n;
#pragma unroll
        for (int mt = 0; mt < 4; ++mt) {
#pragma unroll
            for (int r = 0; r < 4; ++r) {
                int m = mt * 16 + q * 4 + r;
                float val = acc[mt][r] + bias[(g == 0) ? m : (64 + (g - 1) * 64 + m)];
                unsigned short v16 = f2bf(val);
                if (g == 0) {
                    if (m < 32) Qg[(size_t)(b * 4096 + i) * 32 + m] = v16;
                    else        Kg[(size_t)(b * 4096 + i) * 32 + (m - 32)] = v16;
                } else {
                    int cout = (g - 1) * 64 + m;
                    Vg[(size_t)(b * 256 + cout) * 4096 + i] = v16;
                }
            }
        }
    }
}

// ---------------------------------------------------------------------------
// Kernel 2: flash attention + residual.
// Each block: one batch, 64 query rows. Wave w: S/softmax owner of rows
// [16w,16w+16), O owner of channels [64w, 64w+64).  One barrier per j-tile.
// ---------------------------------------------------------------------------
__launch_bounds__(256, 1)
__global__ void attn_kernel(const float* __restrict__ a_p, const float* __restrict__ c_p,
                            const float* __restrict__ gamma_p,
                            const unsigned short* __restrict__ Qg,
                            const unsigned short* __restrict__ Kg,
                            const unsigned short* __restrict__ Vg,
                            float* __restrict__ out)
{
    __shared__ unsigned short Kt[2][64 * 40];  // K tile (j,32) pad-40, dbuf
    __shared__ unsigned short Pt[2][64 * 72];  // P tile (i,64) pad-72 bf16, dbuf
    __shared__ float    alph[2][64];
    __shared__ unsigned flags[2][4];
    __shared__ float    lrow[64];
    __shared__ float    cdl[64];
    __shared__ float    Ot[64 * 257];          // (i, c) fp32, pad-257

    const int t    = threadIdx.x;
    const int blk  = blockIdx.x;
    const int b    = blk & 3;
    const int tile = blk >> 2;
    const int i0   = tile * 64;
    const int lane = t & 63;
    const int w    = t >> 6;
    const int q    = lane >> 4;
    const int n    = lane & 15;

    if (t < 64) cdl[t] = c_p[b * 16384 + tile * 256 + 2 * t];  // cd[b, i0+t]

    // K tile 0 -> Kt[0] (4KB contiguous global read)
    {
        int4v k0 = *(const int4v*)(Kg + (size_t)(b * 4096) * 32 + t * 8);
        *(int4v*)&Kt[0][(t >> 2) * 40 + (t & 3) * 8] = k0;
    }
    // Q A-fragment direct from global: Q[i0+16w+n][q*8 .. +8]
    short8 qf = *(const short8*)(Qg + (size_t)(b * 4096 + i0 + 16 * w + n) * 32 + q * 8);
    __syncthreads();

    float4v sclv = *(const float4v*)&cdl[16 * w + q * 4];
#pragma unroll
    for (int r = 0; r < 4; ++r) sclv[r] *= LOG2E;   // logits in exp2 domain

    float m2[4], l2[4];
#pragma unroll
    for (int r = 0; r < 4; ++r) { m2[r] = -1e30f; l2[r] = 0.f; }
    float4v acc[4][4];
#pragma unroll
    for (int g = 0; g < 4; ++g)
#pragma unroll
        for (int ct = 0; ct < 4; ++ct) acc[g][ct] = (float4v){0.f, 0.f, 0.f, 0.f};

    const float4v zero4 = (float4v){0.f, 0.f, 0.f, 0.f};

    for (int it = 0; it < 64; ++it) {
        const int j0  = it * 64;
        const int cur = it & 1, nxt = cur ^ 1;

        // V B-frags for THIS iter, direct from global (L2-resident): issue early
        short8 vf[4][2];
#pragma unroll
        for (int ct = 0; ct < 4; ++ct)
#pragma unroll
            for (int kc = 0; kc < 2; ++kc)
                vf[ct][kc] = *(const short8*)(Vg + (size_t)(b * 256 + 64 * w + ct * 16 + n) * 4096
                                              + j0 + kc * 32 + q * 8);
        // prefetch next K tile (it=63 reads into V region: in-bounds, unused)
        int4v kreg = *(const int4v*)(Kg + (size_t)(b * 4096 + j0 + 64) * 32 + t * 8);

        // ---- S = Q K^T for my 16 rows x 64 j ----
        float4v sv[4];
#pragma unroll
        for (int jt = 0; jt < 4; ++jt) {
            short8 kf = *(const short8*)&Kt[cur][(jt * 16 + n) * 40 + q * 8];
            sv[jt] = __builtin_amdgcn_mfma_f32_16x16x32_bf16(qf, kf, zero4, 0, 0, 0);
        }

        // ---- online softmax (rows = q*4+r, cols across 16 lanes x 4 jt) ----
        float al[4], pv[4][4];
        bool chg = false;
#pragma unroll
        for (int r = 0; r < 4; ++r) {
            float mr = sv[0][r] * sclv[r];
            mr = fmaxf(mr, sv[1][r] * sclv[r]);
            mr = fmaxf(mr, sv[2][r] * sclv[r]);
            mr = fmaxf(mr, sv[3][r] * sclv[r]);
#pragma unroll
            for (int off = 1; off < 16; off <<= 1) mr = fmaxf(mr, __shfl_xor(mr, off, 64));
            float mn = fmaxf(m2[r], mr);
            al[r] = exp2f(m2[r] - mn);
            chg = chg || (mn != m2[r]);
            m2[r] = mn;
            float s = 0.f;
#pragma unroll
            for (int jt = 0; jt < 4; ++jt) {
                pv[jt][r] = exp2f(sv[jt][r] * sclv[r] - mn);
                s += pv[jt][r];
            }
#pragma unroll
            for (int off = 1; off < 16; off <<= 1) s += __shfl_xor(s, off, 64);
            l2[r] = l2[r] * al[r] + s;
        }

        // ---- P -> LDS (bf16, row-major (i,64) so O-phase reads are A-frags) ----
#pragma unroll
        for (int jt = 0; jt < 4; ++jt)
#pragma unroll
            for (int r = 0; r < 4; ++r)
                Pt[cur][(16 * w + q * 4 + r) * 72 + jt * 16 + n] = f2bf(pv[jt][r]);

        unsigned long long bl = __ballot(chg ? 1 : 0);
        if (n == 0) {
            float4v av = (float4v){al[0], al[1], al[2], al[3]};
            *(float4v*)&alph[cur][16 * w + q * 4] = av;
        }
        if (lane == 0) flags[cur][w] = (bl != 0ull) ? 1u : 0u;

        // write next K tile into alt buffer
        *(int4v*)&Kt[nxt][(t >> 2) * 40 + (t & 3) * 8] = kreg;

        __syncthreads();

        // ---- O phase: my c-slice [64w, 64w+64), all 64 rows ----
#pragma unroll
        for (int g = 0; g < 4; ++g) {
            if (flags[cur][g]) {           // uniform branch; rare after warmup
                float4v av = *(const float4v*)&alph[cur][g * 16 + q * 4];
#pragma unroll
                for (int ct = 0; ct < 4; ++ct)
#pragma unroll
                    for (int r = 0; r < 4; ++r) acc[g][ct][r] *= av[r];
            }
        }
#pragma unroll
        for (int g = 0; g < 4; ++g) {
            short8 pf0 = *(const short8*)&Pt[cur][(g * 16 + n) * 72 + 0 + q * 8];
            short8 pf1 = *(const short8*)&Pt[cur][(g * 16 + n) * 72 + 32 + q * 8];
#pragma unroll
            for (int ct = 0; ct < 4; ++ct) {
                acc[g][ct] = __builtin_amdgcn_mfma_f32_16x16x32_bf16(pf0, vf[ct][0], acc[g][ct], 0, 0, 0);
                acc[g][ct] = __builtin_amdgcn_mfma_f32_16x16x32_bf16(pf1, vf[ct][1], acc[g][ct], 0, 0, 0);
            }
        }
    }

    // ---- epilogue: normalize, transpose via LDS, fuse residual ----
    if (n == 0) {
        float4v lv = (float4v){l2[0], l2[1], l2[2], l2[3]};
        *(float4v*)&lrow[16 * w + q * 4] = lv;
    }
    __syncthreads();
    float gam = gamma_p[0];
#pragma unroll
    for (int g = 0; g < 4; ++g) {
        float4v lv = *(const float4v*)&lrow[g * 16 + q * 4];
        float4v inv;
#pragma unroll
        for (int r = 0; r < 4; ++r) inv[r] = 1.0f / lv[r];
#pragma unroll
        for (int ct = 0; ct < 4; ++ct)
#pragma unroll
            for (int r = 0; r < 4; ++r)
                Ot[(g * 16 + q * 4 + r) * 257 + 64 * w + ct * 16 + n] = acc[g][ct][r] * inv[r];
    }
    __syncthreads();
    for (int pass = 0; pass < 64; ++pass) {
        int c = pass * 4 + (t >> 6);
        int i = t & 63;
        float ov  = Ot[i * 257 + c];
        size_t gi = (size_t)(b * 256 + c) * 4096 + i0 + i;
        float av  = a_p[gi];
        float cdv = cdl[i];
        out[gi] = gam * av * cdv + (1.0f - cdv) * ov;
    }
}

// ---------------------------------------------------------------------------
extern "C" void kernel_launch(void* const* d_in, const int* in_sizes, int n_in,
                              void* d_out, int out_size, void* d_ws, size_t ws_size,
                              hipStream_t stream)
{
    const float* a_p   = (const float*)d_in[0];
    const float* b_p   = (const float*)d_in[1];
    const float* c_p   = (const float*)d_in[2];
    const float* wq    = (const float*)d_in[3];
    const float* bq    = (const float*)d_in[4];
    const float* wk    = (const float*)d_in[5];
    const float* bk    = (const float*)d_in[6];
    const float* wv    = (const float*)d_in[7];
    const float* bv    = (const float*)d_in[8];
    const float* gamma = (const float*)d_in[9];
    float* out = (float*)d_out;

    // workspace: Q (B*N*32), K (B*N*32), V (B*C*N), all bf16
    unsigned short* Qg = (unsigned short*)d_ws;
    unsigned short* Kg = Qg + (size_t)4 * 4096 * 32;
    unsigned short* Vg = Kg + (size_t)4 * 4096 * 32;

    proj_kernel<<<256, 256, 0, stream>>>(a_p, b_p, wq, bq, wk, bk, wv, bv, Qg, Kg, Vg);
    attn_kernel<<<256, 256, 0, stream>>>(a_p, c_p, gamma, Qg, Kg, Vg, out);
}

// Round 2
// 235.551 us; speedup vs baseline: 1.0676x; 1.0676x over previous
//
#include <hip/hip_runtime.h>

#define LOG2E 1.44269504088896340736f

typedef __attribute__((ext_vector_type(8))) short short8;
typedef __attribute__((ext_vector_type(4))) float float4v;
typedef __attribute__((ext_vector_type(2))) float float2v;
typedef __attribute__((ext_vector_type(2))) int int2v;

__device__ inline unsigned short f2bf(float f) {
    union { float f; unsigned u; } v; v.f = f;
    unsigned r = v.u + 0x7fffu + ((v.u >> 16) & 1u);
    return (unsigned short)(r >> 16);
}
__device__ inline float bf2f(unsigned short u) {
    union { unsigned u; float f; } v; v.u = ((unsigned)u) << 16;
    return v.f;
}

// ---------------------------------------------------------------------------
// Kernel 0: convert weights to bf16, concatenated Wbf[320][256]
// rows 0-31 = wq, 32-63 = wk, 64-319 = wv.  grid 80 x 256.
// ---------------------------------------------------------------------------
__global__ void wcvt_kernel(const float* __restrict__ wq, const float* __restrict__ wk,
                            const float* __restrict__ wv, unsigned short* __restrict__ Wbf)
{
    int idx = blockIdx.x * 256 + threadIdx.x;     // 20480 float4s
    int e4  = idx * 4;
    int row = e4 >> 8, col = e4 & 255;
    const float* src = (row < 32) ? (wq + row * 256 + col)
                     : (row < 64) ? (wk + (row - 32) * 256 + col)
                                  : (wv + (row - 64) * 256 + col);
    float4v v = *(const float4v*)src;
    int2v p;
    p.x = (unsigned)f2bf(v[0]) | ((unsigned)f2bf(v[1]) << 16);
    p.y = (unsigned)f2bf(v[2]) | ((unsigned)f2bf(v[3]) << 16);
    *(int2v*)(Wbf + e4) = p;
}

// ---------------------------------------------------------------------------
// Kernel 1: projections.  16-pixel i-tiles, grid 1024 (b = blk&3), block 256.
// Q,K stored (N,32) bf16; V stored (C,N) bf16 with per-64 column permutation
// p = (l&15)*4 + (l>>4)  (matches attn P pack order).
// ---------------------------------------------------------------------------
__launch_bounds__(256, 4)
__global__ void proj_kernel(const float* __restrict__ a_p, const float* __restrict__ b_p,
                            const float* __restrict__ bq, const float* __restrict__ bk,
                            const float* __restrict__ bv,
                            const unsigned short* __restrict__ Wbf,
                            unsigned short* __restrict__ Qg, unsigned short* __restrict__ Kg,
                            unsigned short* __restrict__ Vg)
{
    __shared__ unsigned At[16 * 132];   // a-tile transposed (i, c-pairs) bf16x2
    __shared__ unsigned Bt[16 * 132];

    const int t    = threadIdx.x;
    const int blk  = blockIdx.x;
    const int b    = blk & 3;
    const int t16  = blk >> 2;
    const int i0   = t16 * 16;
    const int lane = t & 63;
    const int w    = t >> 6;
    const int q    = lane >> 4;
    const int n    = lane & 15;

    // ---- stage: each thread loads 2 full c-rows (64B each), packs, transposes ----
    {
        int arr = t >> 7, p = t & 127;
        const float* src = (arr ? b_p : a_p) + ((size_t)(b * 256 + 2 * p)) * 4096 + i0;
        unsigned* dst = arr ? Bt : At;
        float4v r0[4], r1[4];
#pragma unroll
        for (int j4 = 0; j4 < 4; ++j4) r0[j4] = *(const float4v*)(src + j4 * 4);
#pragma unroll
        for (int j4 = 0; j4 < 4; ++j4) r1[j4] = *(const float4v*)(src + 4096 + j4 * 4);
#pragma unroll
        for (int j4 = 0; j4 < 4; ++j4)
#pragma unroll
            for (int jj = 0; jj < 4; ++jj) {
                int i = j4 * 4 + jj;
                dst[i * 132 + p] = (unsigned)f2bf(r0[j4][jj]) | ((unsigned)f2bf(r1[j4][jj]) << 16);
            }
    }
    __syncthreads();

    // ---- GEMM: wave w owns m-tiles {w, w+4, w+8, w+12, w+16} (rows of Wbf) ----
    float4v acc[5];
#pragma unroll
    for (int kk = 0; kk < 5; ++kk) acc[kk] = (float4v){0.f, 0.f, 0.f, 0.f};

#pragma unroll
    for (int kc = 0; kc < 8; ++kc) {
        short8 atf = *(const short8*)((const unsigned short*)At + n * 264 + kc * 32 + q * 8);
        short8 btf = atf;
        if (w >= 2)  // only waves 2,3 own a K m-tile
            btf = *(const short8*)((const unsigned short*)Bt + n * 264 + kc * 32 + q * 8);
#pragma unroll
        for (int kk = 0; kk < 5; ++kk) {
            int mt = w + 4 * kk;
            short8 wf = *(const short8*)(Wbf + (size_t)(mt * 16 + n) * 256 + kc * 32 + q * 8);
            short8 bsel = (mt == 2 || mt == 3) ? btf : atf;
            acc[kk] = __builtin_amdgcn_mfma_f32_16x16x32_bf16(wf, bsel, acc[kk], 0, 0, 0);
        }
    }

    // ---- store (C-layout: row m = mt*16+q*4+r, col i = i0+n) ----
    const int i = i0 + n;
    const int l = i & 63;
    const int pperm = (l & 15) * 4 + (l >> 4);
#pragma unroll
    for (int kk = 0; kk < 5; ++kk) {
        int mt = w + 4 * kk;
#pragma unroll
        for (int r = 0; r < 4; ++r) {
            int mm = mt * 16 + q * 4 + r;
            float bias = (mm < 32) ? bq[mm] : (mm < 64) ? bk[mm - 32] : bv[mm - 64];
            unsigned short v16 = f2bf(acc[kk][r] + bias);
            if (mm < 32)       Qg[(size_t)(b * 4096 + i) * 32 + mm] = v16;
            else if (mm < 64)  Kg[(size_t)(b * 4096 + i) * 32 + (mm - 32)] = v16;
            else               Vg[(size_t)(b * 256 + (mm - 64)) * 4096 + (i >> 6) * 64 + pperm] = v16;
        }
    }
}

// ---------------------------------------------------------------------------
// Kernel 2: flash attention, split-j.  grid 1024: b=blk&3, rt=(blk>>2)&63,
// s=blk>>8.  Block 256 = 4 waves; wave w owns S/softmax of rows [16w,16w+16)
// and O of channels [64w,64w+64).  K,V frags direct from global (L2-hot).
// Writes bf16 partial O + (m,l) per row.
// ---------------------------------------------------------------------------
__launch_bounds__(256, 3)
__global__ void attn_kernel(const unsigned short* __restrict__ Qg,
                            const unsigned short* __restrict__ Kg,
                            const unsigned short* __restrict__ Vg,
                            const float* __restrict__ c_p,
                            unsigned short* __restrict__ Opart, float* __restrict__ ml)
{
    __shared__ unsigned short Pt[2][64 * 72];   // P tile (row, 64 permuted cols), bf16
    __shared__ float    alph[2][64];
    __shared__ unsigned flags[2][4];
    __shared__ float    cdl[64];

    const int t    = threadIdx.x;
    const int blk  = blockIdx.x;
    const int b    = blk & 3;
    const int rt   = (blk >> 2) & 63;
    const int s    = blk >> 8;
    const int i0   = rt * 64;
    const int jbase = s * 1024;
    const int lane = t & 63;
    const int w    = t >> 6;
    const int q    = lane >> 4;
    const int n    = lane & 15;

    if (t < 64) cdl[t] = c_p[b * 16384 + rt * 256 + 2 * t];

    short8 qf = *(const short8*)(Qg + (size_t)(b * 4096 + i0 + 16 * w + n) * 32 + q * 8);
    __syncthreads();

    float4v sclv = *(const float4v*)&cdl[16 * w + q * 4];
#pragma unroll
    for (int r = 0; r < 4; ++r) sclv[r] *= LOG2E;

    float m2[4];
#pragma unroll
    for (int r = 0; r < 4; ++r) m2[r] = -1e30f;
    float4v lacc = (float4v){0.f, 0.f, 0.f, 0.f};
    float4v acc[4][4];
#pragma unroll
    for (int g = 0; g < 4; ++g)
#pragma unroll
        for (int ct = 0; ct < 4; ++ct) acc[g][ct] = (float4v){0.f, 0.f, 0.f, 0.f};

    const float4v zero4 = (float4v){0.f, 0.f, 0.f, 0.f};
    short8 ones;
#pragma unroll
    for (int z = 0; z < 8; ++z) ones[z] = (short)0x3F80;   // bf16 1.0

    const unsigned short* kb = Kg + (size_t)(b * 4096 + jbase + n) * 32 + q * 8;
    const unsigned short* vb = Vg + (size_t)(b * 256 + 64 * w + n) * 4096 + jbase + q * 8;

    for (int it = 0; it < 16; ++it) {
        const int cur = it & 1;

        // V B-frags for this iter (global, L2-hot) — issue first
        short8 vf[4][2];
#pragma unroll
        for (int ct = 0; ct < 4; ++ct)
#pragma unroll
            for (int kc = 0; kc < 2; ++kc)
                vf[ct][kc] = *(const short8*)(vb + (size_t)ct * 16 * 4096 + it * 64 + kc * 32);
        // K B-frags (global, L1/L2-hot)
        short8 kf[4];
#pragma unroll
        for (int jt = 0; jt < 4; ++jt)
            kf[jt] = *(const short8*)(kb + (size_t)(it * 64 + jt * 16) * 32);

        float4v sv[4];
#pragma unroll
        for (int jt = 0; jt < 4; ++jt)
            sv[jt] = __builtin_amdgcn_mfma_f32_16x16x32_bf16(qf, kf[jt], zero4, 0, 0, 0);

        // ---- online softmax (max via 16-lane shfl; sum via MFMA ones-trick) ----
        float al[4], px[4][4];
        bool chg = false;
#pragma unroll
        for (int r = 0; r < 4; ++r) {
            float s0 = sv[0][r] * sclv[r], s1 = sv[1][r] * sclv[r];
            float s2 = sv[2][r] * sclv[r], s3 = sv[3][r] * sclv[r];
            float mr = fmaxf(fmaxf(s0, s1), fmaxf(s2, s3));
#pragma unroll
            for (int off = 1; off < 16; off <<= 1) mr = fmaxf(mr, __shfl_xor(mr, off, 64));
            float mn = fmaxf(m2[r], mr);
            al[r] = exp2f(m2[r] - mn);
            chg = chg || (mn != m2[r]);
            m2[r] = mn;
            px[0][r] = exp2f(s0 - mn); px[1][r] = exp2f(s1 - mn);
            px[2][r] = exp2f(s2 - mn); px[3][r] = exp2f(s3 - mn);
        }

        // ---- P -> LDS, packed b64, permuted col order p = n*4 + jt ----
        unsigned short* pw = &Pt[cur][(16 * w + q * 4) * 72 + n * 4];
#pragma unroll
        for (int r = 0; r < 4; ++r) {
            int2v pd;
            pd.x = (unsigned)f2bf(px[0][r]) | ((unsigned)f2bf(px[1][r]) << 16);
            pd.y = (unsigned)f2bf(px[2][r]) | ((unsigned)f2bf(px[3][r]) << 16);
            *(int2v*)(pw + r * 72) = pd;
        }

        unsigned long long bl = __ballot(chg ? 1 : 0);
        if (n == 0) {
            float4v av = (float4v){al[0], al[1], al[2], al[3]};
            *(float4v*)&alph[cur][16 * w + q * 4] = av;
        }
        if (lane == 0) flags[cur][w] = (bl != 0ull) ? 1u : 0u;

        __syncthreads();

        // ---- O phase ----
#pragma unroll
        for (int g = 0; g < 4; ++g) {
            if (flags[cur][g]) {
                float4v av = *(const float4v*)&alph[cur][g * 16 + q * 4];
#pragma unroll
                for (int ct = 0; ct < 4; ++ct)
#pragma unroll
                    for (int r = 0; r < 4; ++r) acc[g][ct][r] *= av[r];
                if (g == w) {
#pragma unroll
                    for (int r = 0; r < 4; ++r) lacc[r] *= av[r];
                }
            }
            short8 pf0 = *(const short8*)&Pt[cur][(g * 16 + n) * 72 + q * 8];
            short8 pf1 = *(const short8*)&Pt[cur][(g * 16 + n) * 72 + 32 + q * 8];
#pragma unroll
            for (int ct = 0; ct < 4; ++ct) {
                acc[g][ct] = __builtin_amdgcn_mfma_f32_16x16x32_bf16(pf0, vf[ct][0], acc[g][ct], 0, 0, 0);
                acc[g][ct] = __builtin_amdgcn_mfma_f32_16x16x32_bf16(pf1, vf[ct][1], acc[g][ct], 0, 0, 0);
            }
            if (g == w) {
                lacc = __builtin_amdgcn_mfma_f32_16x16x32_bf16(pf0, ones, lacc, 0, 0, 0);
                lacc = __builtin_amdgcn_mfma_f32_16x16x32_bf16(pf1, ones, lacc, 0, 0, 0);
            }
        }
    }

    // ---- epilogue: partial O (bf16) + m,l per row ----
    const size_t obase = (size_t)blk * 16384;
#pragma unroll
    for (int g = 0; g < 4; ++g)
#pragma unroll
        for (int ct = 0; ct < 4; ++ct) {
            int c = 64 * w + ct * 16 + n;
            int i = g * 16 + q * 4;
            int2v pk;
            pk.x = (unsigned)f2bf(acc[g][ct][0]) | ((unsigned)f2bf(acc[g][ct][1]) << 16);
            pk.y = (unsigned)f2bf(acc[g][ct][2]) | ((unsigned)f2bf(acc[g][ct][3]) << 16);
            *(int2v*)(Opart + obase + (size_t)c * 64 + i) = pk;
        }
    if (n == 0) {
#pragma unroll
        for (int r = 0; r < 4; ++r) {
            int row = 16 * w + q * 4 + r;
            ml[(size_t)blk * 128 + row * 2]     = m2[r];
            ml[(size_t)blk * 128 + row * 2 + 1] = lacc[r];
        }
    }
}

// ---------------------------------------------------------------------------
// Kernel 3: combine 4 splits + residual.  grid 256 (b=blk&3, rt=blk>>2).
// ---------------------------------------------------------------------------
__launch_bounds__(256, 4)
__global__ void combine_kernel(const float* __restrict__ a_p, const float* __restrict__ c_p,
                               const float* __restrict__ gamma_p,
                               const unsigned short* __restrict__ Opart,
                               const float* __restrict__ ml, float* __restrict__ out)
{
    __shared__ float wgt[4][64];
    __shared__ float cdl[64];

    const int t   = threadIdx.x;
    const int blk = blockIdx.x;
    const int b   = blk & 3;
    const int rt  = blk >> 2;
    const int i0  = rt * 64;

    if (t < 64) {
        int row = t;
        float m[4], lv[4];
#pragma unroll
        for (int s = 0; s < 4; ++s) {
            int idx = (s << 8) | (rt << 2) | b;
            m[s]  = ml[(size_t)idx * 128 + row * 2];
            lv[s] = ml[(size_t)idx * 128 + row * 2 + 1];
        }
        float M = fmaxf(fmaxf(m[0], m[1]), fmaxf(m[2], m[3]));
        float L = 0.f;
        float e[4];
#pragma unroll
        for (int s = 0; s < 4; ++s) { e[s] = exp2f(m[s] - M); L += lv[s] * e[s]; }
        float invL = 1.0f / L;
#pragma unroll
        for (int s = 0; s < 4; ++s) wgt[s][row] = e[s] * invL;
        cdl[row] = c_p[b * 16384 + rt * 256 + 2 * row];
    }
    __syncthreads();

    const float gam = gamma_p[0];
    const int il = (t & 31) * 2;
    const int cq = t >> 5;
#pragma unroll 4
    for (int k = 0; k < 32; ++k) {
        int c = cq + 8 * k;
        float o0 = 0.f, o1 = 0.f;
#pragma unroll
        for (int s = 0; s < 4; ++s) {
            int idx = (s << 8) | (rt << 2) | b;
            unsigned pr = *(const unsigned*)(Opart + (size_t)idx * 16384 + (size_t)c * 64 + il);
            o0 += wgt[s][il]     * bf2f((unsigned short)(pr & 0xffff));
            o1 += wgt[s][il + 1] * bf2f((unsigned short)(pr >> 16));
        }
        size_t gi = (size_t)(b * 256 + c) * 4096 + i0 + il;
        float2v av = *(const float2v*)(a_p + gi);
        float cd0 = cdl[il], cd1 = cdl[il + 1];
        float2v ov;
        ov[0] = gam * av[0] * cd0 + (1.0f - cd0) * o0;
        ov[1] = gam * av[1] * cd1 + (1.0f - cd1) * o1;
        *(float2v*)(out + gi) = ov;
    }
}

// ---------------------------------------------------------------------------
extern "C" void kernel_launch(void* const* d_in, const int* in_sizes, int n_in,
                              void* d_out, int out_size, void* d_ws, size_t ws_size,
                              hipStream_t stream)
{
    const float* a_p   = (const float*)d_in[0];
    const float* b_p   = (const float*)d_in[1];
    const float* c_p   = (const float*)d_in[2];
    const float* wq    = (const float*)d_in[3];
    const float* bq    = (const float*)d_in[4];
    const float* wk    = (const float*)d_in[5];
    const float* bk    = (const float*)d_in[6];
    const float* wv    = (const float*)d_in[7];
    const float* bv    = (const float*)d_in[8];
    const float* gamma = (const float*)d_in[9];
    float* out = (float*)d_out;

    // workspace layout (ushort elems unless noted):
    // Qg 524288 | Kg 524288 | Vg 4194304 | Wbf 81920 | Opart 16777216 | ml 131072 f32
    unsigned short* Qg    = (unsigned short*)d_ws;
    unsigned short* Kg    = Qg + (size_t)4 * 4096 * 32;
    unsigned short* Vg    = Kg + (size_t)4 * 4096 * 32;
    unsigned short* Wbf   = Vg + (size_t)4 * 256 * 4096;
    unsigned short* Opart = Wbf + (size_t)320 * 256;
    float*          ml    = (float*)(Opart + (size_t)1024 * 16384);

    wcvt_kernel<<<80, 256, 0, stream>>>(wq, wk, wv, Wbf);
    proj_kernel<<<1024, 256, 0, stream>>>(a_p, b_p, bq, bk, bv, Wbf, Qg, Kg, Vg);
    attn_kernel<<<1024, 256, 0, stream>>>(Qg, Kg, Vg, c_p, Opart, ml);
    combine_kernel<<<256, 256, 0, stream>>>(a_p, c_p, gamma, Opart, ml, out);
}